// Round 5
// baseline (128.389 us; speedup 1.0000x reference)
//
#include <hip/hip_runtime.h>

#define TT 256      // T
#define DD 256      // D = H*DK
#define NH 4
#define DKK 64
#define NR 64
#define NB 4        // batch

// ---------------- Kernel 1: fused QKV projection ----------------
// grid (64 row-tiles of 16, 4 col-tiles of 64, 3 projections), block 256.
// Thread (rg,cg) owns row rg, cols {cg, cg+16, cg+32, cg+48}: B-operand LDS
// reads are 16 consecutive rows (stride 68 = 4 mod 32), 4x lane-broadcast ->
// uniform 2-way bank aliasing = free (m136); A-operand is a 16-lane broadcast.
__global__ __launch_bounds__(256) void k_qkv(
    const float* __restrict__ x,
    const float* __restrict__ Wq, const float* __restrict__ bq,
    const float* __restrict__ Wk, const float* __restrict__ bk,
    const float* __restrict__ Wv, const float* __restrict__ bv,
    float* __restrict__ Q, float* __restrict__ K, float* __restrict__ V)
{
    const int z = blockIdx.z;
    const float* __restrict__ W    = (z == 0) ? Wq : (z == 1) ? Wk : Wv;
    const float* __restrict__ bias = (z == 0) ? bq : (z == 1) ? bk : bv;
    float* __restrict__ out        = (z == 0) ? Q  : (z == 1) ? K  : V;
    const int r0 = blockIdx.x * 16, c0 = blockIdx.y * 64;
    __shared__ float xl[16][68];
    __shared__ float wl[64][68];
    const int t = threadIdx.x;
    const int cg = t & 15, rg = t >> 4;
    float acc[4] = {};
    for (int kt = 0; kt < 4; ++kt) {
        const int kb = kt * 64;
        // stage x tile: 16 rows x 16 float4 = 256 float4, one per thread
        {
            const int r = t >> 4, q4 = t & 15;
            *(float4*)&xl[r][q4 * 4] = *(const float4*)&x[(r0 + r) * DD + kb + q4 * 4];
        }
        // stage W tile: 64 rows x 16 float4 = 1024 float4, 4 per thread
        #pragma unroll
        for (int u = 0; u < 4; ++u) {
            const int idx = u * 256 + t;
            const int r = idx >> 4, q4 = idx & 15;
            *(float4*)&wl[r][q4 * 4] = *(const float4*)&W[(c0 + r) * DD + kb + q4 * 4];
        }
        __syncthreads();
        #pragma unroll 4
        for (int d4 = 0; d4 < 64; d4 += 4) {
            const float4 xv = *(const float4*)&xl[rg][d4];
            #pragma unroll
            for (int c = 0; c < 4; ++c) {
                const float4 wv = *(const float4*)&wl[cg + 16 * c][d4];
                acc[c] += xv.x * wv.x + xv.y * wv.y + xv.z * wv.z + xv.w * wv.w;
            }
        }
        __syncthreads();
    }
    const int r = r0 + rg;
    #pragma unroll
    for (int c = 0; c < 4; ++c) {
        const int cc = c0 + cg + 16 * c;
        out[r * DD + cc] = acc[c] + bias[cc];
    }
}

// ---------------- Kernel 2: relational attention ----------------
// grid (16 i-tiles of 16, H, B), block 512 (8 waves -> 2 waves/SIMD at
// 1 block/CU, 149.4 KB LDS). Restructurings vs reference:
//   q.(k_j + rel_k[sm_ij]) = q.k_j + qr[i, sm_ij]                (qr is [16][64])
//   sum_j p_ij (v_j + rel_v[sm_ij]) = P.V + sum_r w[i,r] rel_v_r (w = 64-bin histogram)
// V-tile uses T14 issue-early/write-late: global->reg issued before softmax,
// reg->LDS (over the dead K buffer) after the softmax barrier.
__global__ __launch_bounds__(512) void k_attn(
    const float* __restrict__ Q, const float* __restrict__ K, const float* __restrict__ V,
    const int* __restrict__ SM,
    const float* __restrict__ relk, const float* __restrict__ relv,
    float* __restrict__ AGG)
{
    const int it = blockIdx.x, h = blockIdx.y, b = blockIdx.z;
    const int i0 = it * 16;
    __shared__ float kv[256][68];          // K tile, later reused for V tile (69.6 KB)
    __shared__ float ql[16][68];
    __shared__ float rkl[64][68];
    __shared__ float rvl[64][68];
    __shared__ float sl[16][260];          // scores -> probs
    __shared__ float qrl[16][64];          // q . rel_k per relation
    __shared__ float wlh[16][64];          // histogram: sum of p per relation
    __shared__ union { int sml[16][256]; float aggp[4][16][64]; } uu;  // time-disjoint

    const int t = threadIdx.x;

    // ---- stage (all float4/int4, G13) ----
    if (t < 256) {                         // Q tile: 256 float4
        const int r = t >> 4, q4 = t & 15;
        *(float4*)&ql[r][q4 * 4] = *(const float4*)&Q[(b * TT + i0 + r) * DD + h * DKK + q4 * 4];
    }
    #pragma unroll
    for (int u = 0; u < 2; ++u) {          // rel_k / rel_v: 1024 float4 each
        const int idx = u * 512 + t;
        const int r = idx >> 4, q4 = idx & 15;
        *(float4*)&rkl[r][q4 * 4] = *(const float4*)&relk[r * DD + h * DKK + q4 * 4];
        *(float4*)&rvl[r][q4 * 4] = *(const float4*)&relv[r * DD + h * DKK + q4 * 4];
    }
    #pragma unroll
    for (int u = 0; u < 2; ++u) {          // spatial ids: 1024 int4
        const int idx = u * 512 + t;
        const int i = idx >> 6, j4 = idx & 63;
        *(int4*)&uu.sml[i][j4 * 4] = *(const int4*)&SM[(b * TT + i0 + i) * TT + j4 * 4];
    }
    #pragma unroll
    for (int u = 0; u < 8; ++u) {          // K tile: 4096 float4
        const int idx = u * 512 + t;
        const int j = idx >> 4, q4 = idx & 15;
        *(float4*)&kv[j][q4 * 4] = *(const float4*)&K[(b * TT + j) * DD + h * DKK + q4 * 4];
    }
    __syncthreads();

    // ---- qr[i][r] = q_i . rel_k_r  (8 groups of 64 lanes x 2 i-rows) ----
    {
        const int r = t & 63, ig = t >> 6;
        float a0 = 0.f, a1 = 0.f;
        #pragma unroll 4
        for (int d4 = 0; d4 < 64; d4 += 4) {
            const float4 rk4 = *(const float4*)&rkl[r][d4];
            const float4 q0 = *(const float4*)&ql[ig * 2 + 0][d4];
            const float4 q1 = *(const float4*)&ql[ig * 2 + 1][d4];
            a0 += q0.x * rk4.x + q0.y * rk4.y + q0.z * rk4.z + q0.w * rk4.w;
            a1 += q1.x * rk4.x + q1.y * rk4.y + q1.z * rk4.z + q1.w * rk4.w;
        }
        qrl[ig * 2 + 0][r] = a0;
        qrl[ig * 2 + 1][r] = a1;
    }
    __syncthreads();

    // ---- scores: thread owns column j = t&255, i-half = t>>8; K-row in VGPRs ----
    {
        const int j = t & 255, ih = t >> 8;
        float4 kr[16];
        #pragma unroll
        for (int c = 0; c < 16; ++c) kr[c] = *(const float4*)&kv[j][c * 4];
        #pragma unroll
        for (int ii = 0; ii < 8; ++ii) {
            const int i = ih * 8 + ii;
            float a = 0.f;
            #pragma unroll
            for (int c = 0; c < 16; ++c) {
                const float4 q4 = *(const float4*)&ql[i][c * 4];
                a += q4.x * kr[c].x + q4.y * kr[c].y + q4.z * kr[c].z + q4.w * kr[c].w;
            }
            sl[i][j] = (a + qrl[i][uu.sml[i][j]]) * 0.125f;   // 1/sqrt(64)
        }
    }
    // zero histogram (synced below, before use)
    {
        float* wf = &wlh[0][0];
        wf[t] = 0.f; wf[t + 512] = 0.f;
    }

    // ---- T14 issue-early: V tile global->reg (independent of softmax) ----
    float4 vpre[8];
    #pragma unroll
    for (int u = 0; u < 8; ++u) {
        const int idx = u * 512 + t;
        const int j = idx >> 4, q4 = idx & 15;
        vpre[u] = *(const float4*)&V[(b * TT + j) * DD + h * DKK + q4 * 4];
    }
    __syncthreads();

    // ---- softmax (32 lanes per row, shfl-xor width 32) + histogram ----
    {
        const int row = t >> 5, g = t & 31;
        float vals[8];
        float m = -1e30f;
        #pragma unroll
        for (int jj = 0; jj < 8; ++jj) {
            vals[jj] = sl[row][g + jj * 32];
            m = fmaxf(m, vals[jj]);
        }
        #pragma unroll
        for (int off = 16; off; off >>= 1) m = fmaxf(m, __shfl_xor(m, off, 32));
        float s = 0.f;
        #pragma unroll
        for (int jj = 0; jj < 8; ++jj) { vals[jj] = __expf(vals[jj] - m); s += vals[jj]; }
        #pragma unroll
        for (int off = 16; off; off >>= 1) s += __shfl_xor(s, off, 32);
        const float inv = 1.0f / s;
        #pragma unroll
        for (int jj = 0; jj < 8; ++jj) {
            const float p = vals[jj] * inv;
            sl[row][g + jj * 32] = p;
            atomicAdd(&wlh[row][uu.sml[row][g + jj * 32]], p);
        }
    }
    __syncthreads();   // all K-reads done long ago; softmax results published

    // ---- T14 write-late: V reg->LDS over the dead K buffer ----
    #pragma unroll
    for (int u = 0; u < 8; ++u) {
        const int idx = u * 512 + t;
        const int j = idx >> 4, q4 = idx & 15;
        *(float4*)&kv[j][q4 * 4] = vpre[u];
    }
    __syncthreads();

    // ---- PV: 8 waves = 4 j-quarters x 2 i-halves; 2i x 4d register tile ----
    {
        const int w = t >> 6, l = t & 63;
        const int jq = w >> 1, ih = w & 1;
        const int dg = l & 15, ig = l >> 4;
        const int ia = ih * 8 + ig * 2;
        float4 ac0 = {0,0,0,0}, ac1 = {0,0,0,0};
        const int jb = jq * 64;
        for (int j0 = jb; j0 < jb + 64; j0 += 4) {
            const float4 p0 = *(const float4*)&sl[ia + 0][j0];
            const float4 p1 = *(const float4*)&sl[ia + 1][j0];
            float4 v4;
            v4 = *(const float4*)&kv[j0 + 0][dg * 4];
            ac0.x += p0.x*v4.x; ac0.y += p0.x*v4.y; ac0.z += p0.x*v4.z; ac0.w += p0.x*v4.w;
            ac1.x += p1.x*v4.x; ac1.y += p1.x*v4.y; ac1.z += p1.x*v4.z; ac1.w += p1.x*v4.w;
            v4 = *(const float4*)&kv[j0 + 1][dg * 4];
            ac0.x += p0.y*v4.x; ac0.y += p0.y*v4.y; ac0.z += p0.y*v4.z; ac0.w += p0.y*v4.w;
            ac1.x += p1.y*v4.x; ac1.y += p1.y*v4.y; ac1.z += p1.y*v4.z; ac1.w += p1.y*v4.w;
            v4 = *(const float4*)&kv[j0 + 2][dg * 4];
            ac0.x += p0.z*v4.x; ac0.y += p0.z*v4.y; ac0.z += p0.z*v4.z; ac0.w += p0.z*v4.w;
            ac1.x += p1.z*v4.x; ac1.y += p1.z*v4.y; ac1.z += p1.z*v4.z; ac1.w += p1.z*v4.w;
            v4 = *(const float4*)&kv[j0 + 3][dg * 4];
            ac0.x += p0.w*v4.x; ac0.y += p0.w*v4.y; ac0.z += p0.w*v4.z; ac0.w += p0.w*v4.w;
            ac1.x += p1.w*v4.x; ac1.y += p1.w*v4.y; ac1.z += p1.w*v4.z; ac1.w += p1.w*v4.w;
        }
        *(float4*)&uu.aggp[jq][ia + 0][dg * 4] = ac0;
        *(float4*)&uu.aggp[jq][ia + 1][dg * 4] = ac1;
    }
    __syncthreads();

    // ---- final: reduce j-quarter partials + histogram x rel_v ----
    {
        const int d = t & 63, w = t >> 6;
        const int ia = w * 2;
        float a0 = uu.aggp[0][ia+0][d] + uu.aggp[1][ia+0][d] + uu.aggp[2][ia+0][d] + uu.aggp[3][ia+0][d];
        float a1 = uu.aggp[0][ia+1][d] + uu.aggp[1][ia+1][d] + uu.aggp[2][ia+1][d] + uu.aggp[3][ia+1][d];
        for (int r = 0; r < 64; ++r) {
            const float rv = rvl[r][d];
            a0 += wlh[ia + 0][r] * rv;
            a1 += wlh[ia + 1][r] * rv;
        }
        AGG[(b * TT + i0 + ia + 0) * DD + h * DKK + d] = a0;
        AGG[(b * TT + i0 + ia + 1) * DD + h * DKK + d] = a1;
    }
}

// ---------------- Kernel 3: out projection + bias + residual ----------------
// grid (64 row-tiles of 16, 4 col-tiles of 64), block 256 = 256 blocks (full
// CU coverage; the LN-fused variant capped at 64 blocks = 25% -> reverted).
__global__ __launch_bounds__(256) void k_oproj(
    const float* __restrict__ AGG, const float* __restrict__ Wo,
    const float* __restrict__ bo, const float* __restrict__ x,
    float* __restrict__ OPRE)
{
    const int r0 = blockIdx.x * 16, c0 = blockIdx.y * 64;
    __shared__ float al[16][68];
    __shared__ float wl[64][68];
    const int t = threadIdx.x;
    const int cg = t & 15, rg = t >> 4;
    float acc[4] = {};
    for (int kt = 0; kt < 4; ++kt) {
        const int kb = kt * 64;
        {
            const int r = t >> 4, q4 = t & 15;
            *(float4*)&al[r][q4 * 4] = *(const float4*)&AGG[(r0 + r) * DD + kb + q4 * 4];
        }
        #pragma unroll
        for (int u = 0; u < 4; ++u) {
            const int idx = u * 256 + t;
            const int r = idx >> 4, q4 = idx & 15;
            *(float4*)&wl[r][q4 * 4] = *(const float4*)&Wo[(c0 + r) * DD + kb + q4 * 4];
        }
        __syncthreads();
        #pragma unroll 4
        for (int d4 = 0; d4 < 64; d4 += 4) {
            const float4 av = *(const float4*)&al[rg][d4];
            #pragma unroll
            for (int c = 0; c < 4; ++c) {
                const float4 wv = *(const float4*)&wl[cg + 16 * c][d4];
                acc[c] += av.x * wv.x + av.y * wv.y + av.z * wv.z + av.w * wv.w;
            }
        }
        __syncthreads();
    }
    const int r = r0 + rg;
    #pragma unroll
    for (int c = 0; c < 4; ++c) {
        const int cc = c0 + cg + 16 * c;
        OPRE[r * DD + cc] = acc[c] + bo[cc] + x[r * DD + cc];
    }
}

// ---------------- Kernel 4: LayerNorm + ReLU (one wave per row) ----------------
// grid 256 blocks x 256 threads = 4 rows per block
__global__ __launch_bounds__(256) void k_ln(
    const float* __restrict__ OPRE, const float* __restrict__ gamma,
    const float* __restrict__ beta, float* __restrict__ out)
{
    const int row = blockIdx.x * 4 + (threadIdx.x >> 6);
    const int lane = threadIdx.x & 63;
    const float4 v = *(const float4*)&OPRE[row * DD + lane * 4];
    float s  = v.x + v.y + v.z + v.w;
    float sq = v.x * v.x + v.y * v.y + v.z * v.z + v.w * v.w;
    #pragma unroll
    for (int off = 32; off; off >>= 1) {
        s  += __shfl_xor(s, off, 64);
        sq += __shfl_xor(sq, off, 64);
    }
    const float mu   = s * (1.0f / DD);
    const float rstd = rsqrtf(sq * (1.0f / DD) - mu * mu + 1e-5f);
    const float4 g  = *(const float4*)&gamma[lane * 4];
    const float4 bt = *(const float4*)&beta[lane * 4];
    float4 o;
    o.x = fmaxf((v.x - mu) * rstd * g.x + bt.x, 0.f);
    o.y = fmaxf((v.y - mu) * rstd * g.y + bt.y, 0.f);
    o.z = fmaxf((v.z - mu) * rstd * g.z + bt.z, 0.f);
    o.w = fmaxf((v.w - mu) * rstd * g.w + bt.w, 0.f);
    *(float4*)&out[row * DD + lane * 4] = o;
}

extern "C" void kernel_launch(void* const* d_in, const int* in_sizes, int n_in,
                              void* d_out, int out_size, void* d_ws, size_t ws_size,
                              hipStream_t stream)
{
    (void)in_sizes; (void)n_in; (void)out_size; (void)ws_size;
    const float* x     = (const float*)d_in[0];
    const int*   SM    = (const int*)d_in[1];
    const float* Wq    = (const float*)d_in[2];
    const float* bq    = (const float*)d_in[3];
    const float* Wk    = (const float*)d_in[4];
    const float* bk    = (const float*)d_in[5];
    const float* Wv    = (const float*)d_in[6];
    const float* bv    = (const float*)d_in[7];
    const float* relk  = (const float*)d_in[8];
    const float* relv  = (const float*)d_in[9];
    const float* Wo    = (const float*)d_in[10];
    const float* bo    = (const float*)d_in[11];
    const float* gamma = (const float*)d_in[12];
    const float* beta  = (const float*)d_in[13];
    float* out = (float*)d_out;
    float* ws  = (float*)d_ws;

    const int NTD = NB * TT * DD;   // 262144 floats
    float* Q  = ws;
    float* K  = ws + NTD;
    float* V  = ws + 2 * NTD;
    float* AG = ws + 3 * NTD;
    float* OP = ws + 4 * NTD;

    k_qkv  <<<dim3(64, 4, 3), 256, 0, stream>>>(x, Wq, bq, Wk, bk, Wv, bv, Q, K, V);
    k_attn <<<dim3(16, NH, NB), 512, 0, stream>>>(Q, K, V, SM, relk, relv, AG);
    k_oproj<<<dim3(64, 4), 256, 0, stream>>>(AG, Wo, bo, x, OP);
    k_ln   <<<256, 256, 0, stream>>>(OP, gamma, beta, out);
}